// Round 1
// baseline (252.521 us; speedup 1.0000x reference)
//
#include <hip/hip_runtime.h>
#include <stdint.h>

#define BB 8
#define HH 1024
#define WW 1024
#define RAD 8
#define SEG 64
#define NSEG (HH / SEG)
#define NPIX 8388608.0f

// ws layout:
//   [0..3]   unsigned int fg count
//   [4..7]   float loss sum
//   [16.. ]  uint8 g[B*H*W]  (vertical clamped distance, 0..8)

__global__ __launch_bounds__(256) void vert_kernel(
    const float* __restrict__ targets,
    uint8_t* __restrict__ g,
    unsigned int* __restrict__ cnt)
{
    const int j = blockIdx.x * blockDim.x + threadIdx.x;   // column
    const int s = blockIdx.y;                              // segment
    const int b = blockIdx.z;
    const int i0 = s * SEG;
    const float* tcol = targets + (size_t)b * HH * WW + j;
    uint8_t* gcol = g + (size_t)b * HH * WW + j;

    unsigned int c = 0;
    int d = RAD;
    // down scan: rows [i0-RAD, i0+SEG)
    #pragma unroll 4
    for (int i = i0 - RAD; i < i0 + SEG; ++i) {
        bool f = false;
        if (i >= 0) f = tcol[(size_t)i * WW] > 0.5f;
        d = f ? 0 : min(d + 1, RAD);
        if (i >= i0) {
            gcol[(size_t)i * WW] = (uint8_t)d;
            c += f ? 1u : 0u;
        }
    }
    // up scan: rows [i0+SEG+RAD-1 .. i0]
    d = RAD;
    #pragma unroll 4
    for (int i = i0 + SEG + RAD - 1; i >= i0; --i) {
        if (i >= i0 + SEG) {
            bool f = (i < HH) && (tcol[(size_t)i * WW] > 0.5f);
            d = f ? 0 : min(d + 1, RAD);
        } else {
            int gd = (int)gcol[(size_t)i * WW];
            bool f = (gd == 0);
            d = f ? 0 : min(d + 1, RAD);
            gcol[(size_t)i * WW] = (uint8_t)min(gd, d);
        }
    }
    // wave-reduce fg count, one atomic per wave
    #pragma unroll
    for (int off = 32; off; off >>= 1) c += __shfl_down(c, off, 64);
    if ((threadIdx.x & 63) == 0) atomicAdd(cnt, c);
}

__global__ __launch_bounds__(256) void hloss_kernel(
    const float* __restrict__ probs,
    const uint8_t* __restrict__ g,
    const unsigned int* __restrict__ cnt,
    float* __restrict__ loss_sum)
{
    const int i = blockIdx.x;
    const int b = blockIdx.y;
    const int tx = threadIdx.x;

    __shared__ __attribute__((aligned(16))) float g2s[RAD + WW + RAD];
    __shared__ float wsum[4];

    const size_t row = (size_t)b * HH + i;
    const uint8_t* grow = g + row * WW;

    // stage squared vertical distances into LDS (halo = 64 = cap^2)
    uchar4 v = ((const uchar4*)grow)[tx];
    g2s[RAD + 4 * tx + 0] = (float)(v.x * v.x);
    g2s[RAD + 4 * tx + 1] = (float)(v.y * v.y);
    g2s[RAD + 4 * tx + 2] = (float)(v.z * v.z);
    g2s[RAD + 4 * tx + 3] = (float)(v.w * v.w);
    if (tx < RAD) {
        g2s[tx] = 64.0f;
        g2s[RAD + WW + tx] = 64.0f;
    }
    __syncthreads();

    // class-balance scalars (cnt written by vert_kernel)
    const float S_pos = (float)(*cnt);
    const float S_neg = NPIX - S_pos;
    const float w_pos = fminf((S_neg + 1e-6f) / (S_pos + 1e-6f), 1.0f);
    const float w_negb = (S_pos + 1e-6f) / (S_neg + 1e-6f);

    // 17-tap min-convolution: 4 output pixels per lane, window of 20 floats
    float wbuf[20];
    float4* wv = (float4*)wbuf;
    const float4* src = (const float4*)&g2s[4 * tx];
    #pragma unroll
    for (int k = 0; k < 5; ++k) wv[k] = src[k];

    float d2[4] = {64.0f, 64.0f, 64.0f, 64.0f};
    #pragma unroll
    for (int m = 0; m < 17; ++m) {
        const float cst = (float)((m - 8) * (m - 8));
        #pragma unroll
        for (int p = 0; p < 4; ++p)
            d2[p] = fminf(d2[p], wbuf[p + m] + cst);
    }

    const float4 pr = ((const float4*)(probs + row * WW))[tx];
    const float px[4] = {pr.x, pr.y, pr.z, pr.w};

    float lsum = 0.0f;
    #pragma unroll
    for (int p = 0; p < 4; ++p) {
        float pp = fminf(fmaxf(px[p], 1e-6f), 1.0f - 1e-6f);
        bool y = (wbuf[p + 8] == 0.0f);          // g==0 <=> foreground
        float wb = __expf(-0.125f * d2[p]);      // exp(-d2 / (2*sigma^2))
        float wneg = fminf(w_negb + wb, 1.0f);
        float q = y ? pp : (1.0f - pp);
        float wgt = y ? w_pos : wneg;
        lsum += wgt * (-__logf(q));
    }

    // block reduction -> one atomic per block
    #pragma unroll
    for (int off = 32; off; off >>= 1) lsum += __shfl_down(lsum, off, 64);
    if ((tx & 63) == 0) wsum[tx >> 6] = lsum;
    __syncthreads();
    if (tx == 0) atomicAdd(loss_sum, wsum[0] + wsum[1] + wsum[2] + wsum[3]);
}

__global__ void final_kernel(const float* __restrict__ loss_sum,
                             float* __restrict__ out)
{
    out[0] = loss_sum[0] / NPIX;
}

extern "C" void kernel_launch(void* const* d_in, const int* in_sizes, int n_in,
                              void* d_out, int out_size, void* d_ws, size_t ws_size,
                              hipStream_t stream) {
    const float* probs   = (const float*)d_in[0];
    const float* targets = (const float*)d_in[1];

    unsigned char* ws = (unsigned char*)d_ws;
    unsigned int* cnt = (unsigned int*)ws;
    float* loss_sum   = (float*)(ws + 4);
    uint8_t* g        = (uint8_t*)(ws + 16);

    hipMemsetAsync(d_ws, 0, 16, stream);

    vert_kernel<<<dim3(WW / 256, NSEG, BB), 256, 0, stream>>>(targets, g, cnt);
    hloss_kernel<<<dim3(HH, BB), 256, 0, stream>>>(probs, g, cnt, loss_sum);
    final_kernel<<<1, 1, 0, stream>>>(loss_sum, (float*)d_out);
}

// Round 2
// 134.142 us; speedup vs baseline: 1.8825x; 1.8825x over previous
//
#include <hip/hip_runtime.h>
#include <stdint.h>

#define BB 8
#define HH 1024
#define WW 1024
#define NPIXT (BB * HH * WW)
#define NPIXF 8388608.0f
#define TH 8
#define NRB (HH / TH)
#define WPR 16  // uint64 words per bit-row (1024 bits)

// ws layout: [0..3] uint fg count, [4..7] float loss sum, [64..] uint64 bitmask (1 MB)

__global__ __launch_bounds__(256) void pack_count_kernel(
    const float* __restrict__ tgt,
    uint64_t* __restrict__ bits,
    unsigned int* __restrict__ cnt)
{
    __shared__ unsigned int wcnt[4];
    const int tid = blockIdx.x * 256 + threadIdx.x;
    const int stride = gridDim.x * 256;
    unsigned int c = 0;
    #pragma unroll 4
    for (int p = tid; p < NPIXT; p += stride) {
        float v = tgt[p];
        uint64_t m = __ballot(v > 0.5f);
        if ((threadIdx.x & 63) == 0) {
            bits[p >> 6] = m;
            c += (unsigned int)__popcll(m);
        }
    }
    if ((threadIdx.x & 63) == 0) wcnt[threadIdx.x >> 6] = c;
    __syncthreads();
    if (threadIdx.x == 0)
        atomicAdd(cnt, wcnt[0] + wcnt[1] + wcnt[2] + wcnt[3]);
}

__global__ __launch_bounds__(256) void edt_loss_kernel(
    const float* __restrict__ probs,
    const uint64_t* __restrict__ bits,
    const unsigned int* __restrict__ cnt,
    float* __restrict__ loss_sum)
{
    __shared__ uint64_t brow[TH + 16][WPR];      // 3 KB: rows r0-8 .. r0+TH+7
    __shared__ uint32_t gtw[TH][261];            // 8.3 KB: g bytes, 8B left pad + 12B right pad
    __shared__ float red[4];

    const int t = threadIdx.x;
    const int r0 = blockIdx.x * TH;
    const int b = blockIdx.y;

    // ---- Phase 1: stage bit rows (halo zero-padded) ----
    for (int idx = t; idx < (TH + 16) * WPR; idx += 256) {
        const int r = idx >> 4, w = idx & 15;
        const int gr = r0 - 8 + r;
        uint64_t v = 0;
        if (gr >= 0 && gr < HH) v = bits[((size_t)(b * HH + gr) << 4) + w];
        brow[r][w] = v;
    }
    if (t < TH) {  // horizontal pads: g = 8 (=> g^2 = 64 = cap)
        gtw[t][0] = 0x08080808u; gtw[t][1] = 0x08080808u;
        gtw[t][258] = 0x08080808u; gtw[t][259] = 0x08080808u; gtw[t][260] = 0x08080808u;
    }
    __syncthreads();

    // ---- Phase 2: vertical clamped distance, 4 columns per thread ----
    const int j0 = t << 2;
    const int wj = j0 >> 6;
    const int bj = j0 & 63;
    uint32_t cw[4] = {0, 0, 0, 0};
    #pragma unroll
    for (int r = 0; r < TH + 16; ++r) {
        const uint32_t nib = (uint32_t)((brow[r][wj] >> bj) & 0xFull);
        cw[0] |= (nib & 1u) << r;
        cw[1] |= ((nib >> 1) & 1u) << r;
        cw[2] |= ((nib >> 2) & 1u) << r;
        cw[3] |= ((nib >> 3) & 1u) << r;
    }
    #pragma unroll
    for (int i = 0; i < TH; ++i) {
        uint32_t packed = 0;
        #pragma unroll
        for (int c = 0; c < 4; ++c) {
            const uint32_t w17 = (cw[c] >> i) & 0x1FFFFu;
            const uint32_t down = w17 >> 8;          // center + below
            const uint32_t up = w17 & 0x1FFu;        // center + above
            const int dd = down ? (__ffs(down) - 1) : 9;
            const int du = up ? (__clz((int)up) - 23) : 9;
            const int g = min(min(dd, du), 8);
            packed |= (uint32_t)g << (8 * c);
        }
        gtw[i][2 + t] = packed;
    }
    __syncthreads();

    // ---- Phase 3: horizontal min-conv (integer) + fused loss ----
    const float S_pos = (float)(*cnt);
    const float S_neg = NPIXF - S_pos;
    const float w_pos = fminf((S_neg + 1e-6f) / (S_pos + 1e-6f), 1.0f);
    const float w_negb = (S_pos + 1e-6f) / (S_neg + 1e-6f);

    const float4* prow = (const float4*)(probs + ((size_t)(b * HH + r0) * WW));
    float lsum = 0.0f;

    #pragma unroll
    for (int i = 0; i < TH; ++i) {
        const uint32_t w0 = gtw[i][t];
        const uint32_t w1 = gtw[i][t + 1];
        const uint32_t w2 = gtw[i][t + 2];
        const uint32_t w3 = gtw[i][t + 3];
        const uint32_t w4 = gtw[i][t + 4];
        int gb[20];
        #pragma unroll
        for (int k = 0; k < 4; ++k) {
            gb[k]      = (int)((w0 >> (8 * k)) & 0xFFu);
            gb[4 + k]  = (int)((w1 >> (8 * k)) & 0xFFu);
            gb[8 + k]  = (int)((w2 >> (8 * k)) & 0xFFu);
            gb[12 + k] = (int)((w3 >> (8 * k)) & 0xFFu);
            gb[16 + k] = (int)((w4 >> (8 * k)) & 0xFFu);
        }
        int gs[20];
        #pragma unroll
        for (int m = 0; m < 20; ++m) gs[m] = gb[m] * gb[m];

        int d2i[4] = {64, 64, 64, 64};
        #pragma unroll
        for (int m = 0; m < 17; ++m) {
            const int oc = (m - 8) * (m - 8);
            #pragma unroll
            for (int c = 0; c < 4; ++c) d2i[c] = min(d2i[c], gs[c + m] + oc);
        }

        const float4 pr = prow[i * 256 + t];
        const float pv[4] = {pr.x, pr.y, pr.z, pr.w};
        #pragma unroll
        for (int c = 0; c < 4; ++c) {
            const float pp = fminf(fmaxf(pv[c], 1e-6f), 1.0f - 1e-6f);
            const bool y = (gb[c + 8] == 0);          // center column FG?
            const float q = y ? pp : (1.0f - pp);
            const float wb = __expf(-0.125f * (float)d2i[c]);
            const float wgt = y ? w_pos : fminf(w_negb + wb, 1.0f);
            lsum -= wgt * __logf(q);
        }
    }

    // block reduction -> one atomic per block
    #pragma unroll
    for (int off = 32; off; off >>= 1) lsum += __shfl_down(lsum, off, 64);
    if ((t & 63) == 0) red[t >> 6] = lsum;
    __syncthreads();
    if (t == 0) atomicAdd(loss_sum, red[0] + red[1] + red[2] + red[3]);
}

__global__ void final_kernel(const float* __restrict__ loss_sum,
                             float* __restrict__ out)
{
    out[0] = loss_sum[0] / NPIXF;
}

extern "C" void kernel_launch(void* const* d_in, const int* in_sizes, int n_in,
                              void* d_out, int out_size, void* d_ws, size_t ws_size,
                              hipStream_t stream) {
    const float* probs   = (const float*)d_in[0];
    const float* targets = (const float*)d_in[1];

    unsigned char* ws = (unsigned char*)d_ws;
    unsigned int* cnt = (unsigned int*)ws;
    float* loss_sum   = (float*)(ws + 4);
    uint64_t* bits    = (uint64_t*)(ws + 64);

    hipMemsetAsync(d_ws, 0, 16, stream);

    pack_count_kernel<<<2048, 256, 0, stream>>>(targets, bits, cnt);
    edt_loss_kernel<<<dim3(NRB, BB), 256, 0, stream>>>(probs, bits, cnt, loss_sum);
    final_kernel<<<1, 1, 0, stream>>>(loss_sum, (float*)d_out);
}

// Round 3
// 111.328 us; speedup vs baseline: 2.2683x; 1.2049x over previous
//
#include <hip/hip_runtime.h>
#include <stdint.h>

#define BB 8
#define HH 1024
#define WW 1024
#define NPIXT (BB * HH * WW)
#define NPIXF 8388608.0f
#define TH 4
#define NRB (HH / TH)
#define NEDT (NRB * BB)          // 2048 edt blocks
#define NPACK 1024               // pack blocks
#define WPR 16                   // uint64 words per bit-row

// ws layout:
//   [0      .. 4K)   uint  pcnt[NPACK]   per-block FG counts (written unconditionally)
//   [4K     .. 16K)  float ploss[NEDT]   per-block loss partials (written unconditionally)
//   [16K    .. +1MB) uint64 bits[B*H*W/64]

__global__ __launch_bounds__(256) void pack_count_kernel(
    const float* __restrict__ tgt,
    uint64_t* __restrict__ bits,
    unsigned int* __restrict__ pcnt)
{
    __shared__ unsigned int wcnt[4];
    const int tid = blockIdx.x * 256 + threadIdx.x;
    const int stride = NPACK * 256;
    unsigned int c = 0;
    #pragma unroll 8
    for (int p = tid; p < NPIXT; p += stride) {
        float v = tgt[p];
        uint64_t m = __ballot(v > 0.5f);
        if ((threadIdx.x & 63) == 0) {
            bits[p >> 6] = m;
            c += (unsigned int)__popcll(m);
        }
    }
    #pragma unroll
    for (int off = 32; off; off >>= 1) c += __shfl_down(c, off, 64);
    if ((threadIdx.x & 63) == 0) wcnt[threadIdx.x >> 6] = c;
    __syncthreads();
    if (threadIdx.x == 0)
        pcnt[blockIdx.x] = wcnt[0] + wcnt[1] + wcnt[2] + wcnt[3];
}

__global__ __launch_bounds__(256) void edt_loss_kernel(
    const float* __restrict__ probs,
    const uint64_t* __restrict__ bits,
    const unsigned int* __restrict__ pcnt,
    float* __restrict__ ploss)
{
    __shared__ uint64_t brow[TH + 16][WPR];      // rows r0-8 .. r0+TH+7
    __shared__ uint32_t gtw[TH][264];            // g bytes: 2-word left pad, 3-word right pad
    __shared__ unsigned int cred[4];
    __shared__ float red[4];

    const int t = threadIdx.x;
    const int r0 = blockIdx.x * TH;
    const int b = blockIdx.y;

    // ---- global FG count: reduce pack partials (L2-hot, overlaps staging) ----
    unsigned int myc = pcnt[t] + pcnt[t + 256] + pcnt[t + 512] + pcnt[t + 768];

    // ---- Phase 1: stage bit rows (halo zero-padded) ----
    for (int idx = t; idx < (TH + 16) * WPR; idx += 256) {
        const int r = idx / WPR, w = idx % WPR;
        const int gr = r0 - 8 + r;
        uint64_t v = 0;
        if (gr >= 0 && gr < HH) v = bits[((size_t)(b * HH + gr) << 4) + w];
        brow[r][w] = v;
    }
    if (t < TH) {  // horizontal pads: g = 8 (=> g^2 = 64 = cap)
        gtw[t][0] = 0x08080808u; gtw[t][1] = 0x08080808u;
        gtw[t][258] = 0x08080808u; gtw[t][259] = 0x08080808u; gtw[t][260] = 0x08080808u;
        gtw[t][261] = 0x08080808u; gtw[t][262] = 0x08080808u; gtw[t][263] = 0x08080808u;
    }
    #pragma unroll
    for (int off = 32; off; off >>= 1) myc += __shfl_down(myc, off, 64);
    if ((t & 63) == 0) cred[t >> 6] = myc;
    __syncthreads();

    // ---- Phase 2: vertical clamped distance via bit tricks, 4 cols/thread ----
    const int j0 = t << 2;
    const int wj = j0 >> 6;
    const int bj = j0 & 63;
    uint32_t cw[4] = {0, 0, 0, 0};
    #pragma unroll
    for (int r = 0; r < TH + 16; ++r) {
        const uint32_t nib = (uint32_t)((brow[r][wj] >> bj) & 0xFull);
        cw[0] |= (nib & 1u) << r;
        cw[1] |= ((nib >> 1) & 1u) << r;
        cw[2] |= ((nib >> 2) & 1u) << r;
        cw[3] |= ((nib >> 3) & 1u) << r;
    }
    #pragma unroll
    for (int i = 0; i < TH; ++i) {
        uint32_t packed = 0;
        #pragma unroll
        for (int c = 0; c < 4; ++c) {
            const uint32_t w17 = (cw[c] >> i) & 0x1FFFFu;
            const uint32_t down = w17 >> 8;          // center + below
            const uint32_t up = w17 & 0x1FFu;        // center + above
            const int dd = down ? (__ffs(down) - 1) : 9;
            const int du = up ? (__clz((int)up) - 23) : 9;
            const int g = min(min(dd, du), 8);
            packed |= (uint32_t)g << (8 * c);
        }
        gtw[i][2 + t] = packed;
    }
    __syncthreads();

    // ---- Phase 3: horizontal min-conv (integer) + fused loss ----
    const float S_pos = (float)(cred[0] + cred[1] + cred[2] + cred[3]);
    const float S_neg = NPIXF - S_pos;
    const float w_pos = fminf((S_neg + 1e-6f) / (S_pos + 1e-6f), 1.0f);
    const float w_negb = (S_pos + 1e-6f) / (S_neg + 1e-6f);

    const float4* prow = (const float4*)(probs + ((size_t)(b * HH + r0) * WW));
    float lsum = 0.0f;

    #pragma unroll
    for (int i = 0; i < TH; ++i) {
        const uint32_t w0 = gtw[i][t];
        const uint32_t w1 = gtw[i][t + 1];
        const uint32_t w2 = gtw[i][t + 2];
        const uint32_t w3 = gtw[i][t + 3];
        const uint32_t w4 = gtw[i][t + 4];
        int gb[20];
        #pragma unroll
        for (int k = 0; k < 4; ++k) {
            gb[k]      = (int)((w0 >> (8 * k)) & 0xFFu);
            gb[4 + k]  = (int)((w1 >> (8 * k)) & 0xFFu);
            gb[8 + k]  = (int)((w2 >> (8 * k)) & 0xFFu);
            gb[12 + k] = (int)((w3 >> (8 * k)) & 0xFFu);
            gb[16 + k] = (int)((w4 >> (8 * k)) & 0xFFu);
        }
        int gs[20];
        #pragma unroll
        for (int m = 0; m < 20; ++m) gs[m] = gb[m] * gb[m];

        int d2i[4] = {64, 64, 64, 64};
        #pragma unroll
        for (int m = 0; m < 17; ++m) {
            const int oc = (m - 8) * (m - 8);
            #pragma unroll
            for (int c = 0; c < 4; ++c) d2i[c] = min(d2i[c], gs[c + m] + oc);
        }

        const float4 pr = prow[i * 256 + t];
        const float pv[4] = {pr.x, pr.y, pr.z, pr.w};
        #pragma unroll
        for (int c = 0; c < 4; ++c) {
            const float pp = fminf(fmaxf(pv[c], 1e-6f), 1.0f - 1e-6f);
            const bool y = (gb[c + 8] == 0);          // center column FG?
            const float q = y ? pp : (1.0f - pp);
            const float wb = __expf(-0.125f * (float)d2i[c]);
            const float wgt = y ? w_pos : fminf(w_negb + wb, 1.0f);
            lsum -= wgt * __logf(q);
        }
    }

    #pragma unroll
    for (int off = 32; off; off >>= 1) lsum += __shfl_down(lsum, off, 64);
    if ((t & 63) == 0) red[t >> 6] = lsum;
    __syncthreads();
    if (t == 0)
        ploss[blockIdx.y * NRB + blockIdx.x] = red[0] + red[1] + red[2] + red[3];
}

__global__ __launch_bounds__(256) void final_kernel(
    const float* __restrict__ ploss,
    float* __restrict__ out)
{
    __shared__ float red[4];
    const int t = threadIdx.x;
    float s = 0.0f;
    #pragma unroll
    for (int k = 0; k < NEDT / 256; ++k) s += ploss[k * 256 + t];
    #pragma unroll
    for (int off = 32; off; off >>= 1) s += __shfl_down(s, off, 64);
    if ((t & 63) == 0) red[t >> 6] = s;
    __syncthreads();
    if (t == 0) out[0] = (red[0] + red[1] + red[2] + red[3]) / NPIXF;
}

extern "C" void kernel_launch(void* const* d_in, const int* in_sizes, int n_in,
                              void* d_out, int out_size, void* d_ws, size_t ws_size,
                              hipStream_t stream) {
    const float* probs   = (const float*)d_in[0];
    const float* targets = (const float*)d_in[1];

    unsigned char* ws = (unsigned char*)d_ws;
    unsigned int* pcnt = (unsigned int*)ws;
    float* ploss       = (float*)(ws + 4096);
    uint64_t* bits     = (uint64_t*)(ws + 16384);

    pack_count_kernel<<<NPACK, 256, 0, stream>>>(targets, bits, pcnt);
    edt_loss_kernel<<<dim3(NRB, BB), 256, 0, stream>>>(probs, bits, pcnt, ploss);
    final_kernel<<<1, 256, 0, stream>>>(ploss, (float*)d_out);
}